// Round 8
// baseline (136.371 us; speedup 1.0000x reference)
//
#include <hip/hip_runtime.h>

#define D 128
#define EDGE_CAP 1024
typedef unsigned int uint32;
typedef __bf16 bf16x8 __attribute__((ext_vector_type(8)));
typedef float f32x4 __attribute__((ext_vector_type(4)));
typedef __attribute__((address_space(1))) const void* gas_ptr;
typedef __attribute__((address_space(3))) void* las_ptr;

__device__ __forceinline__ unsigned short f2bf(float f) {
    unsigned u = __float_as_uint(f);
    unsigned r = u + 0x7FFFu + ((u >> 16) & 1u);   // round-to-nearest-even
    return (unsigned short)(r >> 16);
}
__device__ __forceinline__ float bflo(uint32 u) { return __uint_as_float(u << 16); }
__device__ __forceinline__ float bfhi(uint32 u) { return __uint_as_float(u & 0xFFFF0000u); }

__device__ __forceinline__ void fma8(float* acc, uint4 r, float v) {
    acc[0] += v * bflo(r.x); acc[1] += v * bfhi(r.x);
    acc[2] += v * bflo(r.y); acc[3] += v * bfhi(r.y);
    acc[4] += v * bflo(r.z); acc[5] += v * bfhi(r.z);
    acc[6] += v * bflo(r.w); acc[7] += v * bfhi(r.w);
}

// ---------------------------------------------------------------------------
// Fused prep: x->bf16 | CSR row_ptr | W transpose+convert
// ---------------------------------------------------------------------------
__global__ __launch_bounds__(256) void prep_kernel(
    const float* __restrict__ x, unsigned short* __restrict__ xh, int n8,
    const int* __restrict__ row, int* __restrict__ row_ptr,
    int n_nodes, int n_edges,
    const float* __restrict__ Wl, const float* __restrict__ Wr,
    unsigned short* __restrict__ Wlt, unsigned short* __restrict__ Wrt,
    int nbConv, int nbRp) {
    const int b = blockIdx.x;
    if (b < nbConv) {
        const int id = b * 256 + threadIdx.x;
        if (id < n8) {
            const float4* p = (const float4*)x + (size_t)id * 2;
            float4 a = p[0], bb = p[1];
            uint4 o;
            o.x = f2bf(a.x) | ((uint32)f2bf(a.y) << 16);
            o.y = f2bf(a.z) | ((uint32)f2bf(a.w) << 16);
            o.z = f2bf(bb.x) | ((uint32)f2bf(bb.y) << 16);
            o.w = f2bf(bb.z) | ((uint32)f2bf(bb.w) << 16);
            ((uint4*)xh)[id] = o;
        }
    } else if (b < nbConv + nbRp) {
        const int e = (b - nbConv) * 256 + threadIdx.x;
        if (e < n_edges) {
            const int r = row[e];
            const int rp = (e == 0) ? -1 : row[e - 1];
            for (int n = rp + 1; n <= r; ++n) row_ptr[n] = e;
            if (e == n_edges - 1)
                for (int n = r + 1; n <= n_nodes; ++n) row_ptr[n] = n_edges;
        }
    } else {
        const int id = (b - nbConv - nbRp) * 256 + threadIdx.x;   // 0..16383
        if (id < 16384) {
            const int n = id & 127, k = id >> 7;
            Wlt[n * 128 + k] = f2bf(Wl[k * 128 + n]);
            Wrt[n * 128 + k] = f2bf(Wr[k * 128 + n]);
        }
    }
}

// ---------------------------------------------------------------------------
// SpMM bf16, group-per-node, ASYNC gather pipeline via global_load_lds.
// Block = 256 thr = 4 waves = 16 nodes; (col,val) staged in LDS (scv).
// Per wave: ring of 4 LDS slots x 2KB. Each stage() = 2 global_load_lds
// instructions (per-lane global src = gathered row chunk; wave-uniform LDS
// dst) covering 2 edges for each of the wave's 4 groups. 3 double-stages
// (6 loads) kept in flight -- depth set by s_waitcnt vmcnt(4), NOT by VGPRs,
// so the compiler cannot serialize the gathers. sched_barrier(0) after each
// waitcnt pins the ds_read consumption (rule: compiler hoists past waitcnt).
// Slot-reuse safety: stage(T+3,slotK) sits after step-T's sched_barrier(0),
// and slotK's previous ds_read completed at step T-1 (lgkm-forced by fma dep).
// ---------------------------------------------------------------------------
__global__ __launch_bounds__(256) void spmm_bf16_kernel(
    const unsigned short* __restrict__ xh,
    const int* __restrict__ row_ptr,
    const int* __restrict__ col,
    const float* __restrict__ val,
    unsigned short* __restrict__ outlh, int n_nodes) {
    __shared__ int2 scv[EDGE_CAP];          // 8 KB
    __shared__ char gbuf[4][4][2048];       // 32 KB: [wave][slot][2 x 4 x 256B]
    const int tid = threadIdx.x;
    const int n0 = blockIdx.x * 16;
    const int e0 = row_ptr[n0];
    const int e1 = row_ptr[min(n0 + 16, n_nodes)];
    const int ne = e1 - e0;
    const bool fits = (ne <= EDGE_CAP);
    if (fits) {
        for (int t = tid; t < ne; t += 256)
            scv[t] = make_int2(col[e0 + t], __float_as_int(val[e0 + t]));
    }
    __syncthreads();

    const int wv = tid >> 6, lane = tid & 63;
    const int g = lane >> 4, lq = lane & 15;
    const int n = n0 + wv * 4 + g;
    int s = 0, e = 0;
    if (n < n_nodes) { s = row_ptr[n]; e = row_ptr[n + 1]; }
    const int deg = e - s;
    const int ls = s - e0;

    float acc[8] = {0.f, 0.f, 0.f, 0.f, 0.f, 0.f, 0.f, 0.f};

    if (fits) {
        int mdeg = deg;
        mdeg = max(mdeg, __shfl_xor(mdeg, 16, 64));
        mdeg = max(mdeg, __shfl_xor(mdeg, 32, 64));
        const int steps = (mdeg + 1) >> 1;      // 2 edges per group per step

        const char* xb = (const char*)xh;
        char* wbuf = &gbuf[wv][0][0];           // wave-uniform
        const unsigned co = (unsigned)lq * 16u; // lane's 16B chunk in a row

        // (col,val) of my group's edge j; (0, 0.0f) past the end
        auto fc = [&](int j) -> int2 {
            return (j < deg) ? scv[ls + j] : make_int2(0, 0);
        };
        // stage edges (2T, 2T+1) of all 4 groups into slot k
        auto stage = [&](int T, int k) {
            const int2 p0 = fc(2 * T), p1 = fc(2 * T + 1);
            const char* s0 = xb + (size_t)((unsigned)p0.x) * 256u + co;
            const char* s1 = xb + (size_t)((unsigned)p1.x) * 256u + co;
            __builtin_amdgcn_global_load_lds((gas_ptr)s0,
                (las_ptr)(wbuf + k * 2048), 16, 0, 0);
            __builtin_amdgcn_global_load_lds((gas_ptr)s1,
                (las_ptr)(wbuf + k * 2048 + 1024), 16, 0, 0);
        };

        stage(0, 0); stage(1, 1); stage(2, 2);  // 6 loads in flight

        for (int T = 0; T < steps; ++T) {
            const int k = T & 3;
            __builtin_amdgcn_s_waitcnt(0x0F74);   // vmcnt(4): slot k landed
            __builtin_amdgcn_sched_barrier(0);
            const int2 p0 = fc(2 * T), p1 = fc(2 * T + 1);
            const uint4 r0 = *(const uint4*)(wbuf + k * 2048 + g * 256 + lq * 16);
            const uint4 r1 = *(const uint4*)(wbuf + k * 2048 + 1024 + g * 256 + lq * 16);
            fma8(acc, r0, __int_as_float(p0.y));
            fma8(acc, r1, __int_as_float(p1.y));
            stage(T + 3, (T + 3) & 3);
        }
        __builtin_amdgcn_s_waitcnt(0x0F70);       // drain all DMAs
        __builtin_amdgcn_sched_barrier(0);
    } else {
        // rare fallback: block's edge range exceeds LDS cap
        for (int j = 0; j < deg; ++j) {
            const int c = col[s + j];
            const float v = val[s + j];
            const uint4 r = *(const uint4*)&xh[(size_t)c * D + lq * 8];
            fma8(acc, r, v);
        }
    }

    if (n < n_nodes) {
        uint4 o;
        o.x = f2bf(acc[0]) | ((uint32)f2bf(acc[1]) << 16);
        o.y = f2bf(acc[2]) | ((uint32)f2bf(acc[3]) << 16);
        o.z = f2bf(acc[4]) | ((uint32)f2bf(acc[5]) << 16);
        o.w = f2bf(acc[6]) | ((uint32)f2bf(acc[7]) << 16);
        *(uint4*)&outlh[(size_t)n * D + lq * 8] = o;
    }
}

// ---------------------------------------------------------------------------
// MFMA GEMM: out = [out_l_h | xh] @ [Wlt;Wrt]^T + b_l  (K=256 bf16 -> f32)
// ---------------------------------------------------------------------------
__global__ __launch_bounds__(256) void gemm_mfma_kernel(
    const unsigned short* __restrict__ xh,
    const unsigned short* __restrict__ outlh,
    const unsigned short* __restrict__ Wlt,
    const unsigned short* __restrict__ Wrt,
    const float* __restrict__ b_l,
    float* __restrict__ out, int M) {
    const int tid = threadIdx.x;
    const int wid = tid >> 6, lane = tid & 63;
    const int wm = wid >> 1, wn = wid & 1;
    const int m0 = blockIdx.x * 64 + wm * 32;
    const int n0 = wn * 64;
    const int fr = lane & 15;
    const int kofs = (lane >> 4) * 8;

    f32x4 acc[2][4];
#pragma unroll
    for (int mr = 0; mr < 2; ++mr)
#pragma unroll
        for (int nr = 0; nr < 4; ++nr) acc[mr][nr] = (f32x4){0.f, 0.f, 0.f, 0.f};

#pragma unroll
    for (int s = 0; s < 8; ++s) {
        const unsigned short* Abase = (s < 4) ? outlh : xh;
        const unsigned short* Wbase = (s < 4) ? Wlt : Wrt;
        const int k0 = (s & 3) * 32;
        bf16x8 a[2], b[4];
#pragma unroll
        for (int mr = 0; mr < 2; ++mr)
            a[mr] = *(const bf16x8*)&Abase[(m0 + mr * 16 + fr) * D + k0 + kofs];
#pragma unroll
        for (int nr = 0; nr < 4; ++nr)
            b[nr] = *(const bf16x8*)&Wbase[(n0 + nr * 16 + fr) * D + k0 + kofs];
#pragma unroll
        for (int mr = 0; mr < 2; ++mr)
#pragma unroll
            for (int nr = 0; nr < 4; ++nr)
                acc[mr][nr] = __builtin_amdgcn_mfma_f32_16x16x32_bf16(
                    a[mr], b[nr], acc[mr][nr], 0, 0, 0);
    }

    const int r0 = (lane >> 4) * 4;
#pragma unroll
    for (int nr = 0; nr < 4; ++nr) {
        const int ncol = n0 + nr * 16 + fr;
        const float bias = b_l[ncol];
#pragma unroll
        for (int mr = 0; mr < 2; ++mr) {
#pragma unroll
            for (int j = 0; j < 4; ++j) {
                const int m = m0 + mr * 16 + r0 + j;
                if (m < M) out[m * D + ncol] = acc[mr][nr][j] + bias;
            }
        }
    }
}

// ===========================================================================
// Fallback f32 path if ws is too small for bf16 staging.
// ===========================================================================
__global__ void build_rowptr_kernel(const int* __restrict__ row,
                                    int* __restrict__ row_ptr,
                                    int n_nodes, int n_edges) {
    int e = blockIdx.x * blockDim.x + threadIdx.x;
    if (e >= n_edges) return;
    int r = row[e];
    int rp = (e == 0) ? -1 : row[e - 1];
    for (int n = rp + 1; n <= r; ++n) row_ptr[n] = e;
    if (e == n_edges - 1)
        for (int n = r + 1; n <= n_nodes; ++n) row_ptr[n] = n_edges;
}

__global__ __launch_bounds__(128) void spmm_kernel(
    const float* __restrict__ x, const int* __restrict__ row_ptr,
    const int* __restrict__ col, const float* __restrict__ val,
    float* __restrict__ out_l) {
    const int n = blockIdx.x;
    const int d = threadIdx.x;
    const int start = row_ptr[n];
    const int end = row_ptr[n + 1];
    float acc = 0.0f;
    for (int e = start; e < end; ++e)
        acc += val[e] * x[(size_t)col[e] * D + d];
    out_l[(size_t)n * D + d] = acc;
}

__global__ __launch_bounds__(256) void fused_gemm_kernel(
    const float* __restrict__ xin, const float* __restrict__ W_l,
    const float* __restrict__ b_l, const float* __restrict__ W_r,
    float* __restrict__ out, int M) {
    __shared__ float As[64][68];
    __shared__ float Ws[64][132];
    const int tid = threadIdx.x;
    const int tx = tid & 15;
    const int ty = tid >> 4;
    const int ty4 = ty * 4;
    const int m0 = blockIdx.x * 64;
    float acc[4][8];
#pragma unroll
    for (int i = 0; i < 4; ++i)
#pragma unroll
        for (int j = 0; j < 8; ++j) acc[i][j] = 0.0f;
    for (int kt = 0; kt < 4; ++kt) {
        const float* Asrc = (kt < 2) ? out : xin;
        const float* Wsrc = (kt < 2) ? W_l : W_r;
        const int koff = (kt & 1) * 64;
        __syncthreads();
#pragma unroll
        for (int r = 0; r < 4; ++r) {
            const int idx = tid + r * 256;
            const int m = idx >> 4;
            const int kq = idx & 15;
            float4 a = make_float4(0.f, 0.f, 0.f, 0.f);
            if (m0 + m < M)
                a = *(const float4*)&Asrc[(size_t)(m0 + m) * D + koff + kq * 4];
            *(float4*)&As[m][kq * 4] = a;
        }
#pragma unroll
        for (int r = 0; r < 8; ++r) {
            const int idx = tid + r * 256;
            const int k = idx >> 5;
            const int j4 = idx & 31;
            *(float4*)&Ws[k][j4 * 4] =
                *(const float4*)&Wsrc[(size_t)(koff + k) * D + j4 * 4];
        }
        __syncthreads();
#pragma unroll 4
        for (int k = 0; k < 64; ++k) {
            const float a0 = As[ty4 + 0][k], a1 = As[ty4 + 1][k];
            const float a2 = As[ty4 + 2][k], a3 = As[ty4 + 3][k];
            const float4 w0 = *(const float4*)&Ws[k][tx * 4];
            const float4 w1 = *(const float4*)&Ws[k][64 + tx * 4];
            acc[0][0] += a0 * w0.x; acc[0][1] += a0 * w0.y; acc[0][2] += a0 * w0.z; acc[0][3] += a0 * w0.w;
            acc[0][4] += a0 * w1.x; acc[0][5] += a0 * w1.y; acc[0][6] += a0 * w1.z; acc[0][7] += a0 * w1.w;
            acc[1][0] += a1 * w0.x; acc[1][1] += a1 * w0.y; acc[1][2] += a1 * w0.z; acc[1][3] += a1 * w0.w;
            acc[1][4] += a1 * w1.x; acc[1][5] += a1 * w1.y; acc[1][6] += a1 * w1.z; acc[1][7] += a1 * w1.w;
            acc[2][0] += a2 * w0.x; acc[2][1] += a2 * w0.y; acc[2][2] += a2 * w0.z; acc[2][3] += a2 * w0.w;
            acc[2][4] += a2 * w1.x; acc[2][5] += a2 * w1.y; acc[2][6] += a2 * w1.z; acc[2][7] += a2 * w1.w;
            acc[3][0] += a3 * w0.x; acc[3][1] += a3 * w0.y; acc[3][2] += a3 * w0.z; acc[3][3] += a3 * w0.w;
            acc[3][4] += a3 * w1.x; acc[3][5] += a3 * w1.y; acc[3][6] += a3 * w1.z; acc[3][7] += a3 * w1.w;
        }
    }
    const float4 bv0 = *(const float4*)&b_l[tx * 4];
    const float4 bv1 = *(const float4*)&b_l[64 + tx * 4];
#pragma unroll
    for (int i = 0; i < 4; ++i) {
        const int m = m0 + ty4 + i;
        if (m < M) {
            float4 o0, o1;
            o0.x = acc[i][0] + bv0.x; o0.y = acc[i][1] + bv0.y;
            o0.z = acc[i][2] + bv0.z; o0.w = acc[i][3] + bv0.w;
            o1.x = acc[i][4] + bv1.x; o1.y = acc[i][5] + bv1.y;
            o1.z = acc[i][6] + bv1.z; o1.w = acc[i][7] + bv1.w;
            *(float4*)&out[(size_t)m * D + tx * 4] = o0;
            *(float4*)&out[(size_t)m * D + 64 + tx * 4] = o1;
        }
    }
}

static inline size_t align256(size_t x) { return (x + 255) & ~(size_t)255; }

extern "C" void kernel_launch(void* const* d_in, const int* in_sizes, int n_in,
                              void* d_out, int out_size, void* d_ws, size_t ws_size,
                              hipStream_t stream) {
    const float* x   = (const float*)d_in[0];
    const int*   row = (const int*)d_in[1];
    const int*   col = (const int*)d_in[2];
    const float* val = (const float*)d_in[3];
    const float* W_l = (const float*)d_in[4];
    const float* b_l = (const float*)d_in[5];
    const float* W_r = (const float*)d_in[6];
    float* out = (float*)d_out;

    const int n_nodes = in_sizes[0] / D;
    const int n_edges = in_sizes[1];

    const size_t xh_bytes   = (size_t)n_nodes * D * 2;
    const size_t outl_bytes = (size_t)n_nodes * D * 2;
    const size_t wt_bytes   = (size_t)D * D * 2;
    const size_t rp_bytes   = (size_t)(n_nodes + 1) * 4;
    size_t off = 0;
    const size_t xh_off   = off; off += align256(xh_bytes);
    const size_t outl_off = off; off += align256(outl_bytes);
    const size_t wlt_off  = off; off += align256(wt_bytes);
    const size_t wrt_off  = off; off += align256(wt_bytes);
    const size_t rp_off   = off; off += align256(rp_bytes);
    const size_t needed   = off + 65536;

    if (ws_size >= needed) {
        unsigned short* xh    = (unsigned short*)((char*)d_ws + xh_off);
        unsigned short* outlh = (unsigned short*)((char*)d_ws + outl_off);
        unsigned short* Wlt   = (unsigned short*)((char*)d_ws + wlt_off);
        unsigned short* Wrt   = (unsigned short*)((char*)d_ws + wrt_off);
        int* row_ptr          = (int*)((char*)d_ws + rp_off);

        const int n8 = n_nodes * D / 8;
        const int nbConv = (n8 + 255) / 256;
        const int nbRp   = (n_edges + 255) / 256;
        const int nbW    = 64;
        prep_kernel<<<nbConv + nbRp + nbW, 256, 0, stream>>>(
            x, xh, n8, row, row_ptr, n_nodes, n_edges,
            W_l, W_r, Wlt, Wrt, nbConv, nbRp);
        spmm_bf16_kernel<<<(n_nodes + 15) / 16, 256, 0, stream>>>(
            xh, row_ptr, col, val, outlh, n_nodes);
        gemm_mfma_kernel<<<(n_nodes + 63) / 64, 256, 0, stream>>>(
            xh, outlh, Wlt, Wrt, b_l, out, n_nodes);
    } else {
        int* row_ptr = (int*)d_ws;
        build_rowptr_kernel<<<(n_edges + 255) / 256, 256, 0, stream>>>(
            row, row_ptr, n_nodes, n_edges);
        spmm_kernel<<<n_nodes, 128, 0, stream>>>(x, row_ptr, col, val, out);
        fused_gemm_kernel<<<(n_nodes + 63) / 64, 256, 0, stream>>>(
            x, W_l, b_l, W_r, out, n_nodes);
    }
}